// Round 1
// baseline (1070.304 us; speedup 1.0000x reference)
//
#include <hip/hip_runtime.h>

#define B_SZ  32768
#define S_MC  4
#define D_IN  256
#define LAT   8
#define NBINS 300
#define KDIM  1323
#define RNK   4

constexpr int TPB   = 256;
constexpr int KPT   = (KDIM + TPB - 1) / TPB;   // 6
constexpr int BPB   = 4;                        // batch rows per block
constexpr int NPASS = S_MC + 1;                 // 4 samples + mean path

__global__ __launch_bounds__(TPB) void cp_profile_kernel(
    const float* __restrict__ x,       // (B, 256)
    const float* __restrict__ eps,     // (S, B, 8)
    const float* __restrict__ A,       // (300, 4)
    const float* __restrict__ Bm,      // (1323, 4)
    const float* __restrict__ C,       // (8, 4)
    const float* __restrict__ bias,    // (300, 1323)
    const float* __restrict__ mu_w,    // (8, 256)
    const float* __restrict__ mu_b,    // (8,)
    const float* __restrict__ std_w,   // (8, 256)
    const float* __restrict__ std_b,   // (8,)
    const int*   __restrict__ glab,    // (B,)
    float* __restrict__ out)
{
    __shared__ float muh_s[LAT];
    __shared__ float stdh_s[LAT];
    __shared__ float w_s[NPASS][RNK];
    __shared__ float redmax_s[4][NPASS];
    __shared__ float redsum_s[4][NPASS];

    const int tid  = threadIdx.x;
    const int lane = tid & 63;
    const int wid  = tid >> 6;

    // ---- B columns: register-resident for the whole block (same 6 k's in
    //      every pass and every batch row -> no LDS staging needed) ----
    float4 b4[KPT];
    const float4* B4 = reinterpret_cast<const float4*>(Bm);
    #pragma unroll
    for (int i = 0; i < KPT; ++i) {
        const int k = tid + i * TPB;
        b4[i] = (k < KDIM) ? B4[k] : make_float4(0.f, 0.f, 0.f, 0.f);
    }

    for (int bb = 0; bb < BPB; ++bb) {
        const int b = blockIdx.x * BPB + bb;
        const int g = glab[b];

        // bias row (1.6 MB table, L2-resident) -> registers
        float bn[KPT];
        #pragma unroll
        for (int i = 0; i < KPT; ++i) {
            const int k = tid + i * TPB;
            bn[i] = (k < KDIM) ? bias[(size_t)g * KDIM + k] : 0.f;
        }

        // eps prefetch for the w-computation (threads 0..15: s = tid>>2)
        float eps_r[LAT];
        if (tid < 16) {
            const int s = tid >> 2;
            const float* ep = eps + ((size_t)s * B_SZ + b) * LAT;
            #pragma unroll
            for (int j = 0; j < LAT; ++j) eps_r[j] = ep[j];
        }

        // ---- 16 dot products (8 mu, 8 std pre-acts), 4 per wave, float4 ----
        const float4* x4 = reinterpret_cast<const float4*>(x + (size_t)b * D_IN);
        const float4 xv = x4[lane];
        float dotv[4];
        #pragma unroll
        for (int dd = 0; dd < 4; ++dd) {
            const int d = wid * 4 + dd;
            const float4* W4 = reinterpret_cast<const float4*>(
                (d < LAT) ? (mu_w + d * D_IN) : (std_w + (d - LAT) * D_IN));
            const float4 wv = W4[lane];
            float a = xv.x * wv.x + xv.y * wv.y + xv.z * wv.z + xv.w * wv.w;
            #pragma unroll
            for (int off = 32; off > 0; off >>= 1)
                a += __shfl_xor(a, off, 64);
            dotv[dd] = a;
        }

        __syncthreads();   // previous iteration's LDS readers are done
        if (lane == 0) {
            #pragma unroll
            for (int dd = 0; dd < 4; ++dd) {
                const int d = wid * 4 + dd;
                if (d < LAT) {
                    muh_s[d] = dotv[dd] + mu_b[d];
                } else {
                    const float y = dotv[dd] + std_b[d - LAT];
                    stdh_s[d - LAT] = fmaxf(y, 0.f) + log1pf(expf(-fabsf(y)));
                }
            }
        }
        __syncthreads();

        // ---- CP weights w[s][r] = A_n[r] * z[s][r]; s==4 is the mean path ----
        if (tid < 20) {
            const int s = tid >> 2, r = tid & 3;
            float z = 0.f;
            #pragma unroll
            for (int j = 0; j < LAT; ++j) {
                float h = muh_s[j];
                if (s < S_MC) h += stdh_s[j] * eps_r[j];
                z += h * C[j * RNK + r];
            }
            w_s[s][r] = A[g * RNK + r] * z;
        }
        // small outputs (mu_h / std_h, fp32)
        const size_t base_small = (size_t)NPASS * B_SZ * KDIM;
        if (tid >= 32 && tid < 40)
            out[base_small + (size_t)b * LAT + (tid - 32)] = muh_s[tid - 32];
        if (tid >= 40 && tid < 48)
            out[base_small + (size_t)B_SZ * LAT + (size_t)b * LAT + (tid - 40)] = stdh_s[tid - 40];
        __syncthreads();

        // ---- fused 5-pass logits + running max (all register traffic) ----
        float wr[NPASS][RNK];
        #pragma unroll
        for (int s = 0; s < NPASS; ++s)
            #pragma unroll
            for (int r = 0; r < RNK; ++r)
                wr[s][r] = w_s[s][r];

        float lg[NPASS][KPT];
        float lmax[NPASS];
        #pragma unroll
        for (int s = 0; s < NPASS; ++s) lmax[s] = -INFINITY;

        #pragma unroll
        for (int i = 0; i < KPT; ++i) {
            const int   k  = tid + i * TPB;
            const bool  ok = (k < KDIM);
            const float4 bv = b4[i];
            const float  bi = bn[i];
            #pragma unroll
            for (int s = 0; s < NPASS; ++s) {
                float v = fmaf(wr[s][0], bv.x,
                          fmaf(wr[s][1], bv.y,
                          fmaf(wr[s][2], bv.z, wr[s][3] * bv.w))) + bi;
                v = ok ? v : -INFINITY;
                lg[s][i] = v;
                lmax[s]  = fmaxf(lmax[s], v);
            }
        }
        #pragma unroll
        for (int s = 0; s < NPASS; ++s)
            #pragma unroll
            for (int off = 32; off > 0; off >>= 1)
                lmax[s] = fmaxf(lmax[s], __shfl_xor(lmax[s], off, 64));
        if (lane == 0) {
            #pragma unroll
            for (int s = 0; s < NPASS; ++s) redmax_s[wid][s] = lmax[s];
        }
        __syncthreads();

        float m[NPASS], lsum[NPASS];
        #pragma unroll
        for (int s = 0; s < NPASS; ++s) {
            m[s] = fmaxf(fmaxf(redmax_s[0][s], redmax_s[1][s]),
                         fmaxf(redmax_s[2][s], redmax_s[3][s]));
            lsum[s] = 0.f;
        }
        #pragma unroll
        for (int i = 0; i < KPT; ++i) {
            #pragma unroll
            for (int s = 0; s < NPASS; ++s) {
                const float e = __expf(lg[s][i] - m[s]);  // exp(-inf)=0 for pads
                lg[s][i] = e;
                lsum[s] += e;
            }
        }
        #pragma unroll
        for (int s = 0; s < NPASS; ++s)
            #pragma unroll
            for (int off = 32; off > 0; off >>= 1)
                lsum[s] += __shfl_xor(lsum[s], off, 64);
        if (lane == 0) {
            #pragma unroll
            for (int s = 0; s < NPASS; ++s) redsum_s[wid][s] = lsum[s];
        }
        __syncthreads();

        // ---- normalize + streamed (non-temporal) output writes ----
        #pragma unroll
        for (int s = 0; s < NPASS; ++s) {
            const float inv = 1.f / (redsum_s[0][s] + redsum_s[1][s] +
                                     redsum_s[2][s] + redsum_s[3][s]);
            const size_t obase = (s < S_MC)
                ? ((size_t)((size_t)s * B_SZ + b) * KDIM)
                : ((size_t)S_MC * B_SZ * KDIM + (size_t)b * KDIM);
            #pragma unroll
            for (int i = 0; i < KPT; ++i) {
                const int k = tid + i * TPB;
                if (k < KDIM)
                    __builtin_nontemporal_store(lg[s][i] * inv, &out[obase + k]);
            }
        }
    }
}

extern "C" void kernel_launch(void* const* d_in, const int* in_sizes, int n_in,
                              void* d_out, int out_size, void* d_ws, size_t ws_size,
                              hipStream_t stream) {
    const float* x     = (const float*)d_in[0];
    const float* eps   = (const float*)d_in[1];
    const float* A     = (const float*)d_in[2];
    const float* Bm    = (const float*)d_in[3];
    const float* C     = (const float*)d_in[4];
    const float* bias  = (const float*)d_in[5];
    const float* mu_w  = (const float*)d_in[6];
    const float* mu_b  = (const float*)d_in[7];
    const float* std_w = (const float*)d_in[8];
    const float* std_b = (const float*)d_in[9];
    const int*   glab  = (const int*)d_in[10];
    float* out = (float*)d_out;

    cp_profile_kernel<<<B_SZ / BPB, TPB, 0, stream>>>(
        x, eps, A, Bm, C, bias, mu_w, mu_b, std_w, std_b, glab, out);
}